// Round 9
// baseline (479.705 us; speedup 1.0000x reference)
//
#include <hip/hip_runtime.h>
#include <hip/hip_bf16.h>
#include <math.h>

// Problem constants
#define BB 16
#define HH 512
#define LL 4096
#define NFFT 8192
#define LAM 0.001f

typedef __attribute__((ext_vector_type(8))) short short8;
typedef __attribute__((ext_vector_type(4))) float floatx4;

#define R2C 0.70710678118654752f

__device__ __forceinline__ void cmul(float ar, float ai, float br, float bi,
                                     float& cr, float& ci) {
  cr = ar * br - ai * bi;
  ci = ar * bi + ai * br;
}

// W16^e = exp(-2*pi*i*e/16)
constexpr float W16C[8] = {1.f, 0.92387953f, 0.70710678f, 0.38268343f, 0.f,
                           -0.38268343f, -0.70710678f, -0.92387953f};
constexpr float W16S[8] = {0.f, -0.38268343f, -0.70710678f, -0.92387953f, -1.f,
                           -0.92387953f, -0.70710678f, -0.38268343f};
// DIF radix-8 output slot order: slot s holds bin BR8[s]
constexpr int BR8[8] = {0, 4, 2, 6, 1, 5, 3, 7};
// W16 powers pre-permuted to slot order (k = BR8[s])
constexpr float W16CB[8] = {W16C[0], W16C[4], W16C[2], W16C[6],
                            W16C[1], W16C[5], W16C[3], W16C[7]};
constexpr float W16SB[8] = {W16S[0], W16S[4], W16S[2], W16S[6],
                            W16S[1], W16S[5], W16S[3], W16S[7]};

// LDS bank swizzle on complex index: XOR bits[0:3] with bits[4:7].
__device__ __forceinline__ int slotf(int a) { return a ^ ((a >> 4) & 15); }

// ---- 8-point DFT, DIF, output slots in BR8 bin order ----
__device__ __forceinline__ void fft8(float* r, float* i) {
  float t0r = r[0] + r[4], t0i = i[0] + i[4], u0r = r[0] - r[4], u0i = i[0] - i[4];
  float t1r = r[1] + r[5], t1i = i[1] + i[5], u1r = r[1] - r[5], u1i = i[1] - i[5];
  float t2r = r[2] + r[6], t2i = i[2] + i[6], u2r = r[2] - r[6], u2i = i[2] - i[6];
  float t3r = r[3] + r[7], t3i = i[3] + i[7], u3r = r[3] - r[7], u3i = i[3] - i[7];
  float w1r = R2C * (u1r + u1i), w1i = R2C * (u1i - u1r);   // *(R2 - R2 i)
  float w2r = u2i, w2i = -u2r;                               // *(-i)
  float w3r = R2C * (u3i - u3r), w3i = -R2C * (u3r + u3i);   // *(-R2 - R2 i)
  float p0r = t0r + t2r, p0i = t0i + t2i, q0r = t0r - t2r, q0i = t0i - t2i;
  float p1r = t1r + t3r, p1i = t1i + t3i, q1r = t1r - t3r, q1i = t1i - t3i;
  float s1r = q1i, s1i = -q1r;                               // *(-i)
  float v0r = u0r + w2r, v0i = u0i + w2i, x0r = u0r - w2r, x0i = u0i - w2i;
  float v1r = w1r + w3r, v1i = w1i + w3i, x1r = w1r - w3r, x1i = w1i - w3i;
  float y1r = x1i, y1i = -x1r;                               // *(-i)
  r[0] = p0r + p1r; i[0] = p0i + p1i;   // bin 0
  r[1] = p0r - p1r; i[1] = p0i - p1i;   // bin 4
  r[2] = q0r + s1r; i[2] = q0i + s1i;   // bin 2
  r[3] = q0r - s1r; i[3] = q0i - s1i;   // bin 6
  r[4] = v0r + v1r; i[4] = v0i + v1i;   // bin 1
  r[5] = v0r - v1r; i[5] = v0i - v1i;   // bin 5
  r[6] = x0r + y1r; i[6] = x0i + y1i;   // bin 3
  r[7] = x0r - y1r; i[7] = x0i - y1i;   // bin 7
}

// ---- fft8 specialized for x[4..7] == 0 (zero-padded first stage) ----
__device__ __forceinline__ void fft8_pad4(float* r, float* i) {
  float x0r = r[0], x0i = i[0], x1r = r[1], x1i = i[1];
  float x2r = r[2], x2i = i[2], x3r = r[3], x3i = i[3];
  float w1r = R2C * (x1r + x1i), w1i = R2C * (x1i - x1r);   // *(R2 - R2 i)
  float w2r = x2i, w2i = -x2r;                               // *(-i)
  float w3r = R2C * (x3i - x3r), w3i = -R2C * (x3r + x3i);   // *(-R2 - R2 i)
  float p0r = x0r + x2r, p0i = x0i + x2i, q0r = x0r - x2r, q0i = x0i - x2i;
  float p1r = x1r + x3r, p1i = x1i + x3i, q1r = x1r - x3r, q1i = x1i - x3i;
  float s1r = q1i, s1i = -q1r;                               // *(-i)
  float v0r = x0r + w2r, v0i = x0i + w2i, m0r = x0r - w2r, m0i = x0i - w2i;
  float v1r = w1r + w3r, v1i = w1i + w3i, m1r = w1r - w3r, m1i = w1i - w3i;
  float y1r = m1i, y1i = -m1r;                               // *(-i)
  r[0] = p0r + p1r; i[0] = p0i + p1i;
  r[1] = p0r - p1r; i[1] = p0i - p1i;
  r[2] = q0r + s1r; i[2] = q0i + s1i;
  r[3] = q0r - s1r; i[3] = q0i - s1i;
  r[4] = v0r + v1r; i[4] = v0i + v1i;
  r[5] = v0r - v1r; i[5] = v0i - v1i;
  r[6] = m0r + y1r; i[6] = m0i + y1i;
  r[7] = m0r - y1r; i[7] = m0i - y1i;
}

// ---- inverse: input slots in BR8 bin order, output natural, unnormalized x8
__device__ __forceinline__ void ifft8(float* r, float* i) {
  float p0r = r[0] + r[1], p0i = i[0] + i[1];
  float p1r = r[0] - r[1], p1i = i[0] - i[1];
  float q0r = r[2] + r[3], q0i = i[2] + i[3];
  float s1r = r[2] - r[3], s1i = i[2] - i[3];
  float v0r = r[4] + r[5], v0i = i[4] + i[5];
  float v1r = r[4] - r[5], v1i = i[4] - i[5];
  float x0r = r[6] + r[7], x0i = i[6] + i[7];
  float y1r = r[6] - r[7], y1i = i[6] - i[7];
  float q1r = -s1i, q1i = s1r;                               // *(+i)
  float x1r = -y1i, x1i = y1r;                               // *(+i)
  float t0r = p0r + q0r, t0i = p0i + q0i, t2r = p0r - q0r, t2i = p0i - q0i;
  float t1r = p1r + q1r, t1i = p1i + q1i, t3r = p1r - q1r, t3i = p1i - q1i;
  float a0r = v0r + x0r, a0i = v0i + x0i, a2r = v0r - x0r, a2i = v0i - x0i;
  float a1r = v1r + x1r, a1i = v1i + x1i, a3r = v1r - x1r, a3i = v1i - x1i;
  float u1r = R2C * (a1r - a1i), u1i = R2C * (a1r + a1i);    // *(R2 + R2 i)
  float u2r = -a2i, u2i = a2r;                               // *(+i)
  float u3r = -R2C * (a3r + a3i), u3i = R2C * (a3r - a3i);   // *(-R2 + R2 i)
  r[0] = t0r + a0r; i[0] = t0i + a0i;  r[4] = t0r - a0r; i[4] = t0i - a0i;
  r[1] = t1r + u1r; i[1] = t1i + u1i;  r[5] = t1r - u1r; i[5] = t1i - u1i;
  r[2] = t2r + u2r; i[2] = t2i + u2i;  r[6] = t2r - u2r; i[6] = t2i - u2i;
  r[3] = t3r + u3r; i[3] = t3i + u3i;  r[7] = t3r - u3r; i[7] = t3i - u3i;
}

// ---- truncated inverse: only outputs 0..3 (4..7 are discarded padding) ----
__device__ __forceinline__ void ifft8_head4(float* r, float* i) {
  float p0r = r[0] + r[1], p0i = i[0] + i[1];
  float p1r = r[0] - r[1], p1i = i[0] - i[1];
  float q0r = r[2] + r[3], q0i = i[2] + i[3];
  float s1r = r[2] - r[3], s1i = i[2] - i[3];
  float v0r = r[4] + r[5], v0i = i[4] + i[5];
  float v1r = r[4] - r[5], v1i = i[4] - i[5];
  float x0r = r[6] + r[7], x0i = i[6] + i[7];
  float y1r = r[6] - r[7], y1i = i[6] - i[7];
  float q1r = -s1i, q1i = s1r;                               // *(+i)
  float x1r = -y1i, x1i = y1r;                               // *(+i)
  float t0r = p0r + q0r, t0i = p0i + q0i, t2r = p0r - q0r, t2i = p0i - q0i;
  float t1r = p1r + q1r, t1i = p1i + q1i, t3r = p1r - q1r, t3i = p1i - q1i;
  float a0r = v0r + x0r, a0i = v0i + x0i, a2r = v0r - x0r, a2i = v0i - x0i;
  float a1r = v1r + x1r, a1i = v1i + x1i, a3r = v1r - x1r, a3i = v1i - x1i;
  float u1r = R2C * (a1r - a1i), u1i = R2C * (a1r + a1i);    // *(R2 + R2 i)
  float u2r = -a2i, u2i = a2r;                               // *(+i)
  float u3r = -R2C * (a3r + a3i), u3i = R2C * (a3r - a3i);   // *(-R2 + R2 i)
  r[0] = t0r + a0r; i[0] = t0i + a0i;
  r[1] = t1r + u1r; i[1] = t1i + u1i;
  r[2] = t2r + u2r; i[2] = t2i + u2i;
  r[3] = t3r + u3r; i[3] = t3i + u3i;
}

__device__ __forceinline__ float gelu_exact(float y) {
  return 0.5f * y * (1.f + erff(y * 0.70710678118654752f));
}

// ---- generic middle radix-8 DIF phase (tw may live in LDS) ----
template <int LOGJ>
__device__ __forceinline__ void r8_fwd(float2* sb, int t, const float4* tw) {
  const int J = 1 << LOGJ;
  const int j = t & (J - 1);
  const int base = (t >> LOGJ) << (LOGJ + 3);
  float xr[8], xi[8];
#pragma unroll
  for (int s = 0; s < 8; ++s) {
    float2 v = sb[slotf(base + j + (s << LOGJ))];
    xr[s] = v.x; xi[s] = v.y;
  }
  fft8(xr, xi);
#pragma unroll
  for (int q = 0; q < 4; ++q) {
    float4 w = tw[(q << LOGJ) + j];
    float tr, ti;
    cmul(xr[2 * q], xi[2 * q], w.x, w.y, tr, ti);
    sb[slotf(base + (BR8[2 * q] << LOGJ) + j)] = make_float2(tr, ti);
    cmul(xr[2 * q + 1], xi[2 * q + 1], w.z, w.w, tr, ti);
    sb[slotf(base + (BR8[2 * q + 1] << LOGJ) + j)] = make_float2(tr, ti);
  }
}

template <int LOGJ>
__device__ __forceinline__ void r8_inv(float2* sb, int t, const float4* tw) {
  const int J = 1 << LOGJ;
  const int j = t & (J - 1);
  const int base = (t >> LOGJ) << (LOGJ + 3);
  float xr[8], xi[8];
#pragma unroll
  for (int q = 0; q < 4; ++q) {
    float4 w = tw[(q << LOGJ) + j];
    float2 v0 = sb[slotf(base + (BR8[2 * q] << LOGJ) + j)];
    cmul(v0.x, v0.y, w.x, -w.y, xr[2 * q], xi[2 * q]);
    float2 v1 = sb[slotf(base + (BR8[2 * q + 1] << LOGJ) + j)];
    cmul(v1.x, v1.y, w.z, -w.w, xr[2 * q + 1], xi[2 * q + 1]);
  }
  ifft8(xr, xi);
#pragma unroll
  for (int s = 0; s < 8; ++s)
    sb[slotf(base + j + (s << LOGJ))] = make_float2(xr[s], xi[s]);
}

// ---- phase 1 tail: tw1 + scatter (fft already done by caller) ----
__device__ __forceinline__ void p1_scatter(float2* sb, int j, const float4* tw1,
                                           float* xr, float* xi) {
#pragma unroll
  for (int q = 0; q < 4; ++q) {
    float4 w = tw1[(q << 10) + j];
    float tr, ti;
    cmul(xr[2 * q], xi[2 * q], w.x, w.y, tr, ti);
    sb[slotf((BR8[2 * q] << 10) + j)] = make_float2(tr, ti);
    cmul(xr[2 * q + 1], xi[2 * q + 1], w.z, w.w, tr, ti);
    sb[slotf((BR8[2 * q + 1] << 10) + j)] = make_float2(tr, ti);
  }
}

// ---- phase 4: pairwise DFT16 (radix-2 + DFT8 + shfl combine) -> bins ----
// Cluster-local (16 consecutive threads, same wave): no barrier needed.
__device__ __forceinline__ void p4_bins(float2* sb, int t, float* br_, float* bi_) {
  const int p = t >> 1, par = t & 1;
  const int a0 = (p << 4) + par;
  float xr[8], xi[8];
#pragma unroll
  for (int e = 0; e < 8; ++e) {
    float2 v = sb[slotf(a0 + 2 * e)];
    xr[e] = v.x; xi[e] = v.y;
  }
  fft8(xr, xi);
#pragma unroll
  for (int s = 0; s < 8; ++s) {
    float tr, ti;
    if (par) { cmul(xr[s], xi[s], W16CB[s], W16SB[s], tr, ti); }
    else { tr = xr[s]; ti = xi[s]; }
    float orr = __shfl_xor(tr, 1);
    float oii = __shfl_xor(ti, 1);
    br_[s] = par ? (orr - tr) : (tr + orr);
    bi_[s] = par ? (oii - ti) : (ti + oii);
  }
}

// ---- inverse phase 4: bins -> samples back to LDS (cluster-local too) ----
__device__ __forceinline__ void p4_inv(float2* sb, int t, float* br_, float* bi_) {
  const int p = t >> 1, par = t & 1;
  const int a0 = (p << 4) + par;
  float yr[8], yi[8];
#pragma unroll
  for (int s = 0; s < 8; ++s) {
    float orr = __shfl_xor(br_[s], 1);
    float oii = __shfl_xor(bi_[s], 1);
    float er = par ? (orr - br_[s]) : (br_[s] + orr);
    float ei = par ? (oii - bi_[s]) : (bi_[s] + oii);
    if (par) { float tr, ti; cmul(er, ei, W16CB[s], -W16SB[s], tr, ti); er = tr; ei = ti; }
    yr[s] = er; yi[s] = ei;
  }
  ifft8(yr, yi);
#pragma unroll
  for (int e = 0; e < 8; ++e)
    sb[slotf(a0 + 2 * e)] = make_float2(yr[e], yi[e]);
}

// -------- pass -1: twiddle tables (bin order pre-permuted by BR8) ----------
__global__ __launch_bounds__(1024) void twgen_kernel(float4* __restrict__ tw1,
                                                     float4* __restrict__ tw2,
                                                     float4* __restrict__ tw3) {
  const int j = threadIdx.x;
#pragma unroll
  for (int q = 0; q < 4; ++q) {
    const int m0 = BR8[2 * q], m1 = BR8[2 * q + 1];
    float s0, c0, s1, c1;
    const float a1 = -6.283185307179586f / 8192.f;
    sincosf(a1 * (float)(j * m0), &s0, &c0);
    sincosf(a1 * (float)(j * m1), &s1, &c1);
    tw1[(q << 10) + j] = make_float4(c0, s0, c1, s1);
    if (j < 128) {
      const float a2 = -6.283185307179586f / 1024.f;
      sincosf(a2 * (float)(j * m0), &s0, &c0);
      sincosf(a2 * (float)(j * m1), &s1, &c1);
      tw2[(q << 7) + j] = make_float4(c0, s0, c1, s1);
    }
    if (j < 16) {
      const float a3 = -6.283185307179586f / 128.f;
      sincosf(a3 * (float)(j * m0), &s0, &c0);
      sincosf(a3 * (float)(j * m1), &s1, &c1);
      tw3[(q << 4) + j] = make_float4(c0, s0, c1, s1);
    }
  }
}

// -------- pass 0: Wout fp32 -> bf16 ----------------------------------------
__global__ void wconv_kernel(const float* __restrict__ W,
                             __hip_bfloat16* __restrict__ Wb) {
  int i = blockIdx.x * 256 + threadIdx.x;
  Wb[i] = __float2bfloat16(W[i]);
}

// -------- pass 1: squash + D-fold + scrambled spectrum (x 1/N) -------------
__global__ __launch_bounds__(1024)
void kf_kernel(const float* __restrict__ kern, const float* __restrict__ D,
               float* __restrict__ Kf, const float4* __restrict__ tw1,
               const float4* __restrict__ tw2, const float4* __restrict__ tw3) {
  __shared__ __align__(16) float2 sb[NFFT];
  __shared__ __align__(16) float4 ltw2[512];
  __shared__ __align__(16) float4 ltw3[64];
  const int t = threadIdx.x;
  const int h = blockIdx.x;
  const float* kr = kern + (size_t)h * LL;
  if (t < 512) ltw2[t] = tw2[t];
  if (t < 64) ltw3[t] = tw3[t];
  {
    float xr[8], xi[8];
#pragma unroll
    for (int s = 0; s < 4; ++s) {
      float kv = kr[t + (s << 10)];
      float a = fabsf(kv) - LAM;
      float sq = (a > 0.f) ? ((kv > 0.f) ? a : -a) : 0.f;
      xr[s] = sq * (1.f / 8192.f);
      xi[s] = 0.f;
    }
    fft8_pad4(xr, xi);
    p1_scatter(sb, t, tw1, xr, xi);
  }
  __syncthreads();
  r8_fwd<7>(sb, t, ltw2);
  __syncthreads();
  r8_fwd<4>(sb, t, ltw3);
  {
    float br_[8], bi_[8];
    p4_bins(sb, t, br_, bi_);
    const float dsc = D[h] * (1.f / 8192.f);  // skip-term fold: +D/N on every bin
    float4* out4 = (float4*)(Kf + (size_t)h * NFFT * 2) + (t << 2);
#pragma unroll
    for (int q = 0; q < 4; ++q)
      out4[q] = make_float4(br_[2 * q] + dsc, bi_[2 * q],
                            br_[2 * q + 1] + dsc, bi_[2 * q + 1]);
  }
}

// -------- pass 2: FFT conv (h, batch-pair) + GELU -> g bf16 ----------------
__global__ __launch_bounds__(1024)
void fftconv_kernel(const float* __restrict__ u, const float* __restrict__ Kf,
                    __hip_bfloat16* __restrict__ g, const float4* __restrict__ tw1,
                    const float4* __restrict__ tw2, const float4* __restrict__ tw3) {
  __shared__ __align__(16) float2 sb[NFFT];
  __shared__ __align__(16) float4 ltw2[512];
  __shared__ __align__(16) float4 ltw3[64];
  const int t = threadIdx.x;
  const int h = blockIdx.x;
  const int p = blockIdx.y;
  const int b0 = 2 * p, b1 = 2 * p + 1;
  const float* u0 = u + ((size_t)(b0 * HH + h)) * LL;
  const float* u1 = u + ((size_t)(b1 * HH + h)) * LL;

  if (t < 512) ltw2[t] = tw2[t];
  if (t < 64) ltw3[t] = tw3[t];

  {
    float xr[8], xi[8];
#pragma unroll
    for (int s = 0; s < 4; ++s) {
      xr[s] = u0[t + (s << 10)];
      xi[s] = u1[t + (s << 10)];
    }
    fft8_pad4(xr, xi);
    p1_scatter(sb, t, tw1, xr, xi);
  }
  __syncthreads();
  r8_fwd<7>(sb, t, ltw2);
  __syncthreads();
  r8_fwd<4>(sb, t, ltw3);
  {
    float br_[8], bi_[8];
    p4_bins(sb, t, br_, bi_);
    const float4* kf4 = (const float4*)(Kf + (size_t)h * NFFT * 2) + (t << 2);
#pragma unroll
    for (int q = 0; q < 4; ++q) {
      float4 kk = kf4[q];
      float tr, ti;
      cmul(br_[2 * q], bi_[2 * q], kk.x, kk.y, tr, ti);
      br_[2 * q] = tr; bi_[2 * q] = ti;
      cmul(br_[2 * q + 1], bi_[2 * q + 1], kk.z, kk.w, tr, ti);
      br_[2 * q + 1] = tr; bi_[2 * q + 1] = ti;
    }
    p4_inv(sb, t, br_, bi_);
  }
  r8_inv<4>(sb, t, ltw3);
  __syncthreads();
  r8_inv<7>(sb, t, ltw2);
  __syncthreads();
  {
    float xr[8], xi[8];
#pragma unroll
    for (int q = 0; q < 4; ++q) {
      float4 w = tw1[(q << 10) + t];
      float2 v0 = sb[slotf((BR8[2 * q] << 10) + t)];
      cmul(v0.x, v0.y, w.x, -w.y, xr[2 * q], xi[2 * q]);
      float2 v1 = sb[slotf((BR8[2 * q + 1] << 10) + t)];
      cmul(v1.x, v1.y, w.z, -w.w, xr[2 * q + 1], xi[2 * q + 1]);
    }
    ifft8_head4(xr, xi);
    __hip_bfloat16* g0 = g + ((size_t)(b0 * HH + h)) * LL;
    __hip_bfloat16* g1 = g + ((size_t)(b1 * HH + h)) * LL;
#pragma unroll
    for (int s = 0; s < 4; ++s) {
      g0[t + (s << 10)] = __float2bfloat16(gelu_exact(xr[s]));
      g1[t + (s << 10)] = __float2bfloat16(gelu_exact(xi[s]));
    }
  }
}

// -------- pass 3 (fused transpose+GEMM, 512 threads / 8 waves):
// out[b][v][l] = silu(sum_h W[v][h]*g[b][h][l] + bout[v])
// 8 waves = 2(m) x 4(n); per-wave tile 64m x 32n -> acc[4][2] (32 VGPRs).
// Staging 1 int4/thread per operand; deep prefetch: GLOAD for step s+1 is
// issued at the tail of step s-1, so a full compute step covers the latency
// before the vmcnt wait at LWRITE. A-tile [128][40] u16; B-tile swizzled
// blk = (l*4 + (h>>3)) ^ ((l>>3)&7), u16 off h&7 (4-way write, 2-way read).
__global__ __launch_bounds__(512) void gemm_kernel(
    const __hip_bfloat16* __restrict__ Wb, const __hip_bfloat16* __restrict__ g,
    const float* __restrict__ bout, float* __restrict__ out) {
  __shared__ unsigned short At[2][128][40];
  __shared__ unsigned short Bt[2][4096];
  // XCD-chunked decode: 2048 work units, 8 XCDs x 256-unit chunks; vt fastest
  // so the 4 blocks sharing a g-panel sit on the same XCD L2.
  const int id = blockIdx.x;
  const int w = (id & 7) * 256 + (id >> 3);
  const int vt = w & 3;
  const int lt = (w >> 2) & 31;
  const int b = w >> 7;
  const int tid = threadIdx.x;
  const int wave = tid >> 6;
  const int ln = tid & 63;
  const int wr = wave >> 2;        // 0..1 (m)
  const int wc = wave & 3;         // 0..3 (n)
  const int lane16 = ln & 15;
  const int quad = ln >> 4;
  const int lbase0 = lt * 128;

  // staging coords (one int4 per operand per thread)
  const int a_m = tid >> 2;            // 0..127
  const int a_c = (tid & 3) * 8;       // 0,8,16,24
  const int b_h = tid >> 4;            // 0..31
  const int b_l = (tid & 15) * 8;      // 8 consecutive l

  const unsigned short* Ag = (const unsigned short*)Wb + (size_t)(vt * 128) * HH;
  const unsigned short* gb = (const unsigned short*)g + (size_t)b * HH * LL + lbase0;

  floatx4 acc[4][2];
#pragma unroll
  for (int mi = 0; mi < 4; ++mi)
#pragma unroll
    for (int ni = 0; ni < 2; ++ni) acc[mi][ni] = (floatx4){0.f, 0.f, 0.f, 0.f};

  int4 la, lb;
#define GLOAD(K0)                                                         \
  la = *(const int4*)(Ag + (size_t)a_m * HH + (K0) + a_c);                \
  lb = *(const int4*)(gb + (size_t)((K0) + b_h) * LL + b_l);
#define LWRITE(BUF)                                                       \
  *(int4*)&At[BUF][a_m][a_c] = la;                                        \
  {                                                                       \
    unsigned short vs[8];                                                 \
    *(int4*)vs = lb;                                                      \
    _Pragma("unroll") for (int e = 0; e < 8; ++e) {                       \
      const int l = b_l + e;                                              \
      const int blk = (l * 4 + (b_h >> 3)) ^ ((l >> 3) & 7);              \
      Bt[BUF][blk * 8 + (b_h & 7)] = vs[e];                               \
    }                                                                     \
  }

  GLOAD(0);
  LWRITE(0);
  GLOAD(32);          // deep prefetch for step 1, in flight across step 0
  __syncthreads();

  const int kk = quad * 8;
  for (int s = 0; s < 16; ++s) {
    const int cur = s & 1;
    short8 af[4], bf[2];
#pragma unroll
    for (int mi = 0; mi < 4; ++mi)
      af[mi] = *(const short8*)&At[cur][wr * 64 + mi * 16 + lane16][kk];
#pragma unroll
    for (int ni = 0; ni < 2; ++ni) {
      const int nloc = wc * 32 + ni * 16 + lane16;
      const int blk = (nloc * 4 + quad) ^ ((nloc >> 3) & 7);
      bf[ni] = *(const short8*)&Bt[cur][blk * 8];
    }
#pragma unroll
    for (int mi = 0; mi < 4; ++mi)
#pragma unroll
      for (int ni = 0; ni < 2; ++ni)
        acc[mi][ni] = __builtin_amdgcn_mfma_f32_16x16x32_bf16(af[mi], bf[ni],
                                                              acc[mi][ni], 0, 0, 0);
    if (s < 15) {
      LWRITE(cur ^ 1);              // waits on GLOAD(s+1), issued a full step ago
      if (s < 14) GLOAD((s + 2) * 32);
      __syncthreads();
    }
  }

#pragma unroll
  for (int mi = 0; mi < 4; ++mi) {
#pragma unroll
    for (int r = 0; r < 4; ++r) {
      const int m = vt * 128 + wr * 64 + mi * 16 + quad * 4 + r;
      const float bias = bout[m];
#pragma unroll
      for (int ni = 0; ni < 2; ++ni) {
        const int n = lbase0 + wc * 32 + ni * 16 + lane16;
        float y = acc[mi][ni][r] + bias;
        y = y / (1.f + __expf(-y));
        out[((size_t)(b * HH + m)) * LL + n] = y;
      }
    }
  }
#undef GLOAD
#undef LWRITE
}

extern "C" void kernel_launch(void* const* d_in, const int* in_sizes, int n_in,
                              void* d_out, int out_size, void* d_ws, size_t ws_size,
                              hipStream_t stream) {
  const float* u = (const float*)d_in[0];
  const float* kern = (const float*)d_in[1];
  const float* D = (const float*)d_in[2];
  const float* Wout = (const float*)d_in[3];
  const float* bout = (const float*)d_in[4];
  float* out = (float*)d_out;

  char* ws = (char*)d_ws;
  const size_t KF_BYTES = (size_t)HH * NFFT * sizeof(float2);
  const size_t G_BYTES = (size_t)BB * HH * LL * 2;
  float* Kf = (float*)ws;  // interleaved (re,im) pairs, scrambled order
  __hip_bfloat16* g = (__hip_bfloat16*)(ws + KF_BYTES);
  __hip_bfloat16* Wb = (__hip_bfloat16*)(ws + KF_BYTES + 2 * G_BYTES);
  float4* tw1 = (float4*)(ws + KF_BYTES + G_BYTES);  // 64 KB
  float4* tw2 = tw1 + 4 * 1024;                      // 8 KB
  float4* tw3 = tw2 + 4 * 128;                       // 1 KB

  twgen_kernel<<<dim3(1), dim3(1024), 0, stream>>>(tw1, tw2, tw3);
  wconv_kernel<<<dim3((HH * HH) / 256), dim3(256), 0, stream>>>(Wout, Wb);
  kf_kernel<<<dim3(HH), dim3(1024), 0, stream>>>(kern, D, Kf, tw1, tw2, tw3);
  fftconv_kernel<<<dim3(HH, BB / 2), dim3(1024), 0, stream>>>(u, Kf, g, tw1, tw2, tw3);
  gemm_kernel<<<dim3(2048), dim3(512), 0, stream>>>(Wb, g, bout, out);
}